// Round 12
// baseline (818.805 us; speedup 1.0000x reference)
//
#include <hip/hip_runtime.h>
#include <hip/hip_bf16.h>
#include <math.h>

typedef unsigned int  u32;
typedef unsigned short u16;
typedef unsigned char u8;

#define BTn   192
#define NQn   64
#define NCn   1024
#define Cd    384
#define Hn    8
#define DHn   48
#define HIDn  1536
#define ROWSX (BTn*NQn)     /* 12288 */
#define ROWSC (BTn*NCn)     /* 196608 */
#define ATT_SCALE 0.14433756729740643f
#define CBc   64            /* batch chunk: kvb = 100 MB, L3-resident */

typedef __bf16 bf16x8 __attribute__((ext_vector_type(8)));
typedef float  f32x4  __attribute__((ext_vector_type(4)));

#define GLL16(gp, lp) __builtin_amdgcn_global_load_lds( \
    (const __attribute__((address_space(1))) void*)(gp), \
    (__attribute__((address_space(3))) void*)(lp), 16, 0, 0)

__device__ __forceinline__ float bf2f(u32 u) {
  union { u32 i; float f; } v; v.i = u << 16; return v.f;
}
__device__ __forceinline__ u16 f2bf(float f) {
  union { float f; u32 i; } v; v.f = f;
  u32 x = v.i;
  x += 0x7fffu + ((x >> 16) & 1u);
  return (u16)(x >> 16);
}
__device__ __forceinline__ void decode8(uint4 r, float* v) {
  v[0]=bf2f(r.x & 0xffffu); v[1]=bf2f(r.x >> 16);
  v[2]=bf2f(r.y & 0xffffu); v[3]=bf2f(r.y >> 16);
  v[4]=bf2f(r.z & 0xffffu); v[5]=bf2f(r.z >> 16);
  v[6]=bf2f(r.w & 0xffffu); v[7]=bf2f(r.w >> 16);
}
__device__ __forceinline__ float gelu_f(float x) {
  float x3 = x*x*x;
  float z = 0.7978845608028654f*x + 0.035677408136300125f*x3;
  float e = __expf(2.f*z);
  float th = 1.f - 2.f/(e+1.f);
  return 0.5f*x*(1.f+th);
}

// ---------------- mask decode (robust to u8 / i32 / bf16 / f32 storage) ---
__global__ void decode_mask_kernel(const u8* __restrict__ m, u8* __restrict__ keep) {
  __shared__ int flags[3];
  int t = threadIdx.x;
  if (t < 3) flags[t] = 0;
  __syncthreads();
  int nonbin = 0, oddset = 0, low01 = 0;
  for (int i = t; i < ROWSX; i += 256) {
    u32 b = m[i];
    if (b > 1u) nonbin = 1;
    if ((i & 3) && b) oddset = 1;
    if (((i & 3) < 2) && b) low01 = 1;
  }
  if (nonbin) flags[0] = 1;
  if (oddset) flags[1] = 1;
  if (low01)  flags[2] = 1;
  __syncthreads();
  int mode = flags[0] ? (flags[2] ? 2 : 3) : (flags[1] ? 1 : 0);
  for (int i = t; i < ROWSX; i += 256) {
    u8 k;
    if (mode == 2)      k = (m[2*i] | m[2*i+1]) ? 1 : 0;
    else if (mode == 3) k = (((const float*)m)[i] != 0.f) ? 1 : 0;
    else if (mode == 1) k = m[i] ? 1 : 0;
    else                k = (((const int*)m)[i] != 0) ? 1 : 0;
    keep[i] = k;
  }
}

// ---------------- per-row LayerNorm stats: (mean, rstd) -------------------
template<int SRCF32>
__global__ __launch_bounds__(256) void row_stats_kernel(
    const void* __restrict__ srcv, float* __restrict__ stats, float eps)
{
  const int row  = blockIdx.x * 4 + (threadIdx.x >> 6);
  const int lane = threadIdx.x & 63;
  float s = 0.f, s2 = 0.f;
  if (SRCF32) {
    const float2* p = (const float2*)((const float*)srcv + (size_t)row*Cd);
    #pragma unroll
    for (int i = 0; i < 3; i++) {
      float2 u = p[lane + 64*i];
      s += u.x + u.y; s2 += u.x*u.x + u.y*u.y;
    }
  } else {
    const u32* p = (const u32*)((const u16*)srcv + (size_t)row*Cd);
    #pragma unroll
    for (int i = 0; i < 3; i++) {
      u32 u = p[lane + 64*i];
      float a = bf2f(u & 0xffffu), b = bf2f(u >> 16);
      s += a + b; s2 += a*a + b*b;
    }
  }
  #pragma unroll
  for (int o = 32; o >= 1; o >>= 1) { s += __shfl_xor(s, o); s2 += __shfl_xor(s2, o); }
  if (lane == 0) {
    float mean = s * (1.0f/Cd);
    float var  = s2 * (1.0f/Cd) - mean*mean;
    var = var > 0.f ? var : 0.f;
    stats[2*row]   = mean;
    stats[2*row+1] = rsqrtf(var + eps);
  }
}

// ---------------- fused LayerNorm -> bf16 (wave per row, x only) ----------
template<int AFF, int SRCF32>
__global__ __launch_bounds__(256) void lnorm_kernel(
    const void* __restrict__ srcv, const float* __restrict__ gw,
    const float* __restrict__ bw, u16* __restrict__ dst, float eps)
{
  const int row  = blockIdx.x * 4 + (threadIdx.x >> 6);
  const int lane = threadIdx.x & 63;
  float v[6];
  if (SRCF32) {
    const float2* p = (const float2*)((const float*)srcv + (size_t)row*Cd);
    #pragma unroll
    for (int i = 0; i < 3; i++) { float2 u = p[lane + 64*i]; v[2*i]=u.x; v[2*i+1]=u.y; }
  } else {
    const u32* p = (const u32*)((const u16*)srcv + (size_t)row*Cd);
    #pragma unroll
    for (int i = 0; i < 3; i++) { u32 u = p[lane + 64*i]; v[2*i]=bf2f(u&0xffffu); v[2*i+1]=bf2f(u>>16); }
  }
  float s  = v[0]+v[1]+v[2]+v[3]+v[4]+v[5];
  float s2 = v[0]*v[0]+v[1]*v[1]+v[2]*v[2]+v[3]*v[3]+v[4]*v[4]+v[5]*v[5];
  #pragma unroll
  for (int o = 32; o >= 1; o >>= 1) { s += __shfl_xor(s, o); s2 += __shfl_xor(s2, o); }
  float mean = s * (1.0f/Cd);
  float var  = s2 * (1.0f/Cd) - mean*mean;
  var = var > 0.f ? var : 0.f;
  float rstd = rsqrtf(var + eps);
  u32* d32 = (u32*)(dst + (size_t)row*Cd);
  #pragma unroll
  for (int i = 0; i < 3; i++) {
    float y0 = (v[2*i]   - mean) * rstd;
    float y1 = (v[2*i+1] - mean) * rstd;
    if (AFF) {
      float2 gg = *(const float2*)(gw + 2*(lane + 64*i));
      float2 bb = *(const float2*)(bw + 2*(lane + 64*i));
      y0 = y0*gg.x + bb.x;
      y1 = y1*gg.y + bb.y;
    }
    d32[lane + 64*i] = (u32)f2bf(y0) | ((u32)f2bf(y1) << 16);
  }
}

// ------- batched weight transpose+convert: W[K][N] f32 -> WT[N][K] bf16 ---
struct WPack {
  const float* W[5];
  u16* WT[5];
  int K[5];
  int N[5];
  int off[6];
};
__global__ __launch_bounds__(256) void wconvt_all_kernel(WPack p) {
  __shared__ u16 tile[64][66];
  const int bid = blockIdx.x;
  int s = 0;
  #pragma unroll
  for (int i = 1; i < 5; i++) if (bid >= p.off[i]) s = i;
  const float* W = p.W[s];
  u16* WT = p.WT[s];
  const int K = p.K[s], N = p.N[s];
  const int lb = bid - p.off[s];
  const int t  = threadIdx.x;
  const int nt = N >> 6;
  const int bk = lb / nt, bn = lb % nt;
  const int q  = t >> 6;
  const int nl = t & 63;
  #pragma unroll
  for (int r = 0; r < 16; r++) {
    int k = q*16 + r;
    tile[nl][k] = f2bf(W[(size_t)(bk*64 + k)*N + bn*64 + nl]);
  }
  __syncthreads();
  #pragma unroll
  for (int r = 0; r < 16; r++) {
    int n = q*16 + r;
    WT[(size_t)(bn*64 + n)*K + bk*64 + nl] = tile[n][nl];
  }
}

// ---------------- MFMA GEMM 128x128 (4 waves): 3-buffer depth-2 -----------
template<int GEL, int RES, int RF32, int OF32, int SCL>
__global__ __launch_bounds__(256) void mgemm_kernel(
    const u16* __restrict__ A, const u16* __restrict__ WT,
    const float* __restrict__ bias, const void* __restrict__ resv,
    void* __restrict__ Coutv, int M, int N, int K, int nx)
{
  __shared__ u16 As[3][4096];
  __shared__ u16 Bs[3][4096];
  const int t = threadIdx.x;
  const int w = t >> 6, l = t & 63, l15 = l & 15, g = l >> 4;

  const int nwg = gridDim.x;
  const int bid = blockIdx.x;
  const int wg  = (bid & 7) * (nwg >> 3) + (bid >> 3);
  const int n0 = (wg % nx) * 128, m0 = (wg / nx) * 128;
  const int wm = (w & 1) * 64, wn = (w >> 1) * 64;

  const int arow = t >> 2;
  const int swk  = (t >> 3) & 3;
  const int acol = ((t & 3) ^ swk) * 8;
  const u16* Ag = A  + (size_t)(m0 + arow) * K + acol;
  const u16* Wg = WT + (size_t)(n0 + arow) * K + acol;
  const size_t rowskip = (size_t)64 * K;

  const int xk   = (l15 >> 1) & 3;
  const int goff = ((g ^ xk) << 3);

  f32x4 acc[4][4];
  #pragma unroll
  for (int i = 0; i < 4; i++)
    #pragma unroll
    for (int j = 0; j < 4; j++) acc[i][j] = (f32x4){0.f, 0.f, 0.f, 0.f};

  const int nIter = K >> 5;

#define STAGE(nb, kk) do { \
    GLL16(Ag + (kk),           &As[nb][t*8]); \
    GLL16(Ag + (kk) + rowskip, &As[nb][2048 + t*8]); \
    GLL16(Wg + (kk),           &Bs[nb][t*8]); \
    GLL16(Wg + (kk) + rowskip, &Bs[nb][2048 + t*8]); \
  } while (0)

#define BODY(BUF, IT) do { \
    const int it_ = (IT); \
    if (it_ + 2 < nIter) { \
      STAGE((BUF + 2) % 3, (it_ + 2) << 5); \
      asm volatile("s_waitcnt vmcnt(8)" ::: "memory"); \
    } else if (it_ + 1 < nIter) { \
      asm volatile("s_waitcnt vmcnt(4)" ::: "memory"); \
    } else { \
      asm volatile("s_waitcnt vmcnt(0)" ::: "memory"); \
    } \
    __builtin_amdgcn_s_barrier(); \
    __builtin_amdgcn_sched_barrier(0); \
    { \
      bf16x8 af[4], bfv[4]; \
      _Pragma("unroll") \
      for (int i = 0; i < 4; i++) \
        af[i] = *(const bf16x8*)&As[BUF][(wm + i*16 + l15)*32 + goff]; \
      _Pragma("unroll") \
      for (int j = 0; j < 4; j++) \
        bfv[j] = *(const bf16x8*)&Bs[BUF][(wn + j*16 + l15)*32 + goff]; \
      _Pragma("unroll") \
      for (int i = 0; i < 4; i++) \
        _Pragma("unroll") \
        for (int j = 0; j < 4; j++) \
          acc[i][j] = __builtin_amdgcn_mfma_f32_16x16x32_bf16(bfv[j], af[i], acc[i][j], 0, 0, 0); \
    } \
    __builtin_amdgcn_sched_barrier(0); \
    __builtin_amdgcn_s_barrier(); \
  } while (0)

  STAGE(0, 0);
  STAGE(1, 32);
  for (int it0 = 0; it0 < nIter; it0 += 3) {
    BODY(0, it0);
    BODY(1, it0 + 1);
    BODY(2, it0 + 2);
  }
#undef BODY
#undef STAGE

  const float* resf = (const float*)resv;
  const u16*   resb = (const u16*)resv;
  float* Cf = (float*)Coutv;
  u16*   Cb = (u16*)Coutv;
  #pragma unroll
  for (int j = 0; j < 4; j++) {
    const int nb = n0 + wn + j*16 + g*4;
    const float4 bv = *(const float4*)&bias[nb];
    #pragma unroll
    for (int i = 0; i < 4; i++) {
      const int m = m0 + wm + i*16 + l15;
      float c0 = acc[i][j][0] + bv.x;
      float c1 = acc[i][j][1] + bv.y;
      float c2 = acc[i][j][2] + bv.z;
      float c3 = acc[i][j][3] + bv.w;
      if (SCL) { c0 *= ATT_SCALE; c1 *= ATT_SCALE; c2 *= ATT_SCALE; c3 *= ATT_SCALE; }
      if (GEL) { c0 = gelu_f(c0); c1 = gelu_f(c1); c2 = gelu_f(c2); c3 = gelu_f(c3); }
      if (RES) {
        if (RF32) {
          float4 r = *(const float4*)&resf[(size_t)m*N + nb];
          c0 += r.x; c1 += r.y; c2 += r.z; c3 += r.w;
        } else {
          uint2 r = *(const uint2*)&resb[(size_t)m*N + nb];
          c0 += bf2f(r.x & 0xffffu); c1 += bf2f(r.x >> 16);
          c2 += bf2f(r.y & 0xffffu); c3 += bf2f(r.y >> 16);
        }
      }
      if (OF32) {
        *(float4*)&Cf[(size_t)m*N + nb] = make_float4(c0, c1, c2, c3);
      } else {
        uint2 pk = make_uint2((u32)f2bf(c0) | ((u32)f2bf(c1) << 16),
                              (u32)f2bf(c2) | ((u32)f2bf(c3) << 16));
        *(uint2*)&Cb[(size_t)m*N + nb] = pk;
      }
    }
  }
}

// ------- MFMA GEMM 128x256, fused-LN A (reg-staged), B via GLL16 ----------
// A = LN(Araw)[*g+b] computed during staging from per-row (mean,rstd) stats.
// A loads issued at body top, LN+ds_write at body bottom (latency hidden by
// the MFMA block). B 3-buffer GLL16 depth-2. Counted vmcnt: bottom leaves
// exactly B(it+2) (2 ops) in flight.
template<int AF32, int AFF, int GEL>
__global__ __launch_bounds__(512, 4) void mgemm256ln_kernel(
    const void* __restrict__ Av, const float* __restrict__ stats,
    const float* __restrict__ gw, const float* __restrict__ bw,
    const u16* __restrict__ WT, const float* __restrict__ bias,
    u16* __restrict__ Cout, int M, int N, int K, int nx)
{
  __shared__ u16 As[3][4096];   // 128 x 32
  __shared__ u16 Bs[3][8192];   // 256 x 32
  __shared__ float gls[Cd], bls[Cd];
  const int t = threadIdx.x;                 // 0..511
  const int w = t >> 6, l = t & 63, l15 = l & 15, g = l >> 4;

  const int nwg = gridDim.x;
  const int bid = blockIdx.x;
  const int wg  = (bid & 7) * (nwg >> 3) + (bid >> 3);
  const int n0 = (wg % nx) * 256, m0 = (wg / nx) * 128;
  const int wm = (w & 1) * 64, wn = (w >> 1) * 64;   // wn 0..192

  const int arow = t >> 2;                   // 0..127
  const int swk  = (t >> 3) & 3;
  const int acol = ((t & 3) ^ swk) * 8;      // pre-swizzled col group
  const float* Af = (const float*)Av + (size_t)(m0 + arow) * K + acol;
  const u16*   Ab = (const u16*)Av   + (size_t)(m0 + arow) * K + acol;
  const u16* Wg = WT + (size_t)(n0 + arow) * K + acol;
  const size_t rowskipB = (size_t)128 * K;

  const float mean = stats[2*(m0 + arow)];
  const float rstd = stats[2*(m0 + arow) + 1];

  const int xk   = (l15 >> 1) & 3;
  const int goff = ((g ^ xk) << 3);

  f32x4 acc[4][4];
  #pragma unroll
  for (int i = 0; i < 4; i++)
    #pragma unroll
    for (int j = 0; j < 4; j++) acc[i][j] = (f32x4){0.f, 0.f, 0.f, 0.f};

  const int nIter = K >> 5;   // 12 (K=384); divisible by 3

  // preload gamma/beta to LDS, then full drain (keeps vm counts uniform)
  if (AFF) {
    for (int i = t; i < Cd; i += 512) { gls[i] = gw[i]; bls[i] = bw[i]; }
  }
  asm volatile("s_waitcnt vmcnt(0) lgkmcnt(0)" ::: "memory");
  __builtin_amdgcn_s_barrier();
  __builtin_amdgcn_sched_barrier(0);

#define LNWRITE(nb, kkA, A0, A1, AU) do { \
    float yv[8]; \
    if (AF32) { yv[0]=(A0).x; yv[1]=(A0).y; yv[2]=(A0).z; yv[3]=(A0).w; \
                yv[4]=(A1).x; yv[5]=(A1).y; yv[6]=(A1).z; yv[7]=(A1).w; } \
    else { decode8((AU), yv); } \
    _Pragma("unroll") \
    for (int j_ = 0; j_ < 8; j_++) yv[j_] = (yv[j_] - mean) * rstd; \
    if (AFF) { \
      const float4 g0_ = *(const float4*)&gls[acol + (kkA)]; \
      const float4 g1_ = *(const float4*)&gls[acol + (kkA) + 4]; \
      const float4 b0_ = *(const float4*)&bls[acol + (kkA)]; \
      const float4 b1_ = *(const float4*)&bls[acol + (kkA) + 4]; \
      yv[0]=yv[0]*g0_.x+b0_.x; yv[1]=yv[1]*g0_.y+b0_.y; \
      yv[2]=yv[2]*g0_.z+b0_.z; yv[3]=yv[3]*g0_.w+b0_.w; \
      yv[4]=yv[4]*g1_.x+b1_.x; yv[5]=yv[5]*g1_.y+b1_.y; \
      yv[6]=yv[6]*g1_.z+b1_.z; yv[7]=yv[7]*g1_.w+b1_.w; \
    } \
    u16 e_[8]; \
    _Pragma("unroll") \
    for (int j_ = 0; j_ < 8; j_++) e_[j_] = f2bf(yv[j_]); \
    uint4 pk_ = make_uint4((u32)e_[0] | ((u32)e_[1] << 16), \
                           (u32)e_[2] | ((u32)e_[3] << 16), \
                           (u32)e_[4] | ((u32)e_[5] << 16), \
                           (u32)e_[6] | ((u32)e_[7] << 16)); \
    *(uint4*)&As[nb][t*8] = pk_; \
  } while (0)

  // prologue: A(0) regs -> LN -> As[0]; B(0),B(1) GLL16
  {
    float4 p0, p1; uint4 pu;
    if (AF32) { p0 = *(const float4*)(Af); p1 = *(const float4*)(Af + 4); }
    else      { pu = *(const uint4*)(Ab); }
    GLL16(Wg,                 &Bs[0][t*8]);
    GLL16(Wg + rowskipB,      &Bs[0][4096 + t*8]);
    GLL16(Wg + 32,            &Bs[1][t*8]);
    GLL16(Wg + 32 + rowskipB, &Bs[1][4096 + t*8]);
    asm volatile("s_waitcnt vmcnt(4)" ::: "memory");   // A(0) regs ready
    LNWRITE(0, 0, p0, p1, pu);
    asm volatile("s_waitcnt vmcnt(2) lgkmcnt(0)" ::: "memory");  // B(0) in LDS
    __builtin_amdgcn_s_barrier();
    __builtin_amdgcn_sched_barrier(0);
  }

#define BODY(BUF, IT) do { \
    const int it_ = (IT); \
    const int kkA = (it_ + 1) << 5; \
    float4 q0, q1; uint4 qu; \
    if (it_ + 1 < nIter) { \
      if (AF32) { q0 = *(const float4*)(Af + kkA); q1 = *(const float4*)(Af + kkA + 4); } \
      else      { qu = *(const uint4*)(Ab + kkA); } \
    } \
    if (it_ + 2 < nIter) { \
      const int kkB = (it_ + 2) << 5; \
      GLL16(Wg + kkB,            &Bs[(BUF+2)%3][t*8]); \
      GLL16(Wg + kkB + rowskipB, &Bs[(BUF+2)%3][4096 + t*8]); \
    } \
    __builtin_amdgcn_sched_barrier(0); \
    { \
      bf16x8 af[4], bfv[4]; \
      _Pragma("unroll") \
      for (int i = 0; i < 4; i++) \
        af[i] = *(const bf16x8*)&As[BUF][(wm + i*16 + l15)*32 + goff]; \
      _Pragma("unroll") \
      for (int j = 0; j < 4; j++) \
        bfv[j] = *(const bf16x8*)&Bs[BUF][(wn + j*16 + l15)*32 + goff]; \
      _Pragma("unroll") \
      for (int i = 0; i < 4; i++) \
        _Pragma("unroll") \
        for (int j = 0; j < 4; j++) \
          acc[i][j] = __builtin_amdgcn_mfma_f32_16x16x32_bf16(bfv[j], af[i], acc[i][j], 0, 0, 0); \
    } \
    __builtin_amdgcn_sched_barrier(0); \
    if (it_ + 1 < nIter) { \
      if (it_ + 2 < nIter) asm volatile("s_waitcnt vmcnt(2)" ::: "memory"); \
      else                 asm volatile("s_waitcnt vmcnt(0)" ::: "memory"); \
      LNWRITE((BUF+1)%3, kkA, q0, q1, qu); \
      asm volatile("s_waitcnt lgkmcnt(0)" ::: "memory"); \
      __builtin_amdgcn_sched_barrier(0); \
      __builtin_amdgcn_s_barrier(); \
      __builtin_amdgcn_sched_barrier(0); \
    } \
  } while (0)

  for (int it0 = 0; it0 < nIter; it0 += 3) {
    BODY(0, it0);
    BODY(1, it0 + 1);
    BODY(2, it0 + 2);
  }
#undef BODY
#undef LNWRITE

  #pragma unroll
  for (int j = 0; j < 4; j++) {
    const int nb = n0 + wn + j*16 + g*4;
    const float4 bv = *(const float4*)&bias[nb];
    #pragma unroll
    for (int i = 0; i < 4; i++) {
      const int m = m0 + wm + i*16 + l15;
      float c0 = acc[i][j][0] + bv.x;
      float c1 = acc[i][j][1] + bv.y;
      float c2 = acc[i][j][2] + bv.z;
      float c3 = acc[i][j][3] + bv.w;
      if (GEL) { c0 = gelu_f(c0); c1 = gelu_f(c1); c2 = gelu_f(c2); c3 = gelu_f(c3); }
      uint2 pk = make_uint2((u32)f2bf(c0) | ((u32)f2bf(c1) << 16),
                            (u32)f2bf(c2) | ((u32)f2bf(c3) << 16));
      *(uint2*)&Cout[(size_t)m*N + nb] = pk;
    }
  }
}

// ---------------- flash attention, MFMA, one block per (b,h) --------------
__global__ __launch_bounds__(256) void fattn_kernel(
    const u16* __restrict__ qb, const u16* __restrict__ kvb,
    const u8* __restrict__ keep, u16* __restrict__ ob, int b0)
{
  __shared__ u16 Qs[64*72];
  __shared__ u16 Ks[64*72];
  __shared__ u16 Vt[48*72];
  __shared__ u16 Ps[4][16*72];

  const int t = threadIdx.x;
  const int w = t >> 6, l = t & 63, l15 = l & 15, g = l >> 4;
  const int h = blockIdx.x, bz = blockIdx.y;
  const int b = b0 + bz;
  const int wq = w * 16;
  const int krow0 = t / 6, kp0 = t % 6;
  const int krow1 = (256 + t) / 6, kp1 = (256 + t) % 6;   // t<128
  const int vdq = (t >> 4) * 4, vkq = (t & 15) * 4;       // t<192

  for (int i = t; i < 2304; i += 256) { ((u32*)Qs)[i] = 0; ((u32*)Ks)[i] = 0; }
  __syncthreads();

  for (int i = t; i < 384; i += 256) {
    int row = i / 6, p = i % 6;
    *(uint4*)&Qs[row*72 + p*8] =
        *(const uint4*)(qb + (size_t)(b*NQn + row)*Cd + h*DHn + p*8);
  }

  u32 kw = *(const u32*)&keep[b*NQn + wq + g*4];
  float kf[4];
  #pragma unroll
  for (int r = 0; r < 4; r++) kf[r] = ((kw >> (8*r)) & 0xffu) ? 1.f : 0.f;

  float mrow[4], lrow[4];
  f32x4 oacc[3];
  #pragma unroll
  for (int r = 0; r < 4; r++) { mrow[r] = kf[r] > 0.f ? -3.0e38f : 0.f; lrow[r] = 0.f; }
  #pragma unroll
  for (int d = 0; d < 3; d++) oacc[d] = (f32x4){0.f, 0.f, 0.f, 0.f};

  auto loadKV = [&](int kt, uint4& KR0, uint4& KR1, uint2* V) {
    const u16* base = kvb + ((size_t)bz*NCn + (size_t)kt*64) * (2*(size_t)Cd);
    KR0 = *(const uint4*)(base + (size_t)krow0*(2*Cd) + h*DHn + kp0*8);
    if (t < 128)
      KR1 = *(const uint4*)(base + (size_t)krow1*(2*Cd) + h*DHn + kp1*8);
    if (t < 192) {
      const u16* vs = base + (size_t)vkq*(2*Cd) + Cd + h*DHn + vdq;
      V[0] = *(const uint2*)(vs);
      V[1] = *(const uint2*)(vs + 2*Cd);
      V[2] = *(const uint2*)(vs + 4*Cd);
      V[3] = *(const uint2*)(vs + 6*Cd);
    }
  };
  auto writeKV = [&](const uint4& KR0, const uint4& KR1, const uint2* V) {
    *(uint4*)&Ks[krow0*72 + kp0*8] = KR0;
    if (t < 128) *(uint4*)&Ks[krow1*72 + kp1*8] = KR1;
    if (t < 192) {
      #pragma unroll
      for (int jj = 0; jj < 4; jj++) {
        u16 o4[4] = {((const u16*)&V[0])[jj], ((const u16*)&V[1])[jj],
                     ((const u16*)&V[2])[jj], ((const u16*)&V[3])[jj]};
        *(uint2*)&Vt[(vdq+jj)*72 + vkq] = *(uint2*)o4;
      }
    }
  };

  bf16x8 qf0, qf1;
  auto compute = [&]() {
    f32x4 sf[4];
    #pragma unroll
    for (int f = 0; f < 4; f++) {
      bf16x8 ka = *(const bf16x8*)&Ks[(f*16 + l15)*72 + g*8];
      bf16x8 kb = *(const bf16x8*)&Ks[(f*16 + l15)*72 + 32 + g*8];
      f32x4 z = (f32x4){0.f, 0.f, 0.f, 0.f};
      z = __builtin_amdgcn_mfma_f32_16x16x32_bf16(qf0, ka, z, 0, 0, 0);
      sf[f] = __builtin_amdgcn_mfma_f32_16x16x32_bf16(qf1, kb, z, 0, 0, 0);
    }
    float p[4][4], pmax[4];
    #pragma unroll
    for (int r = 0; r < 4; r++) {
      float pm = fmaxf(fmaxf(sf[0][r], sf[1][r]), fmaxf(sf[2][r], sf[3][r]));
      #pragma unroll
      for (int s = 1; s < 16; s <<= 1) pm = fmaxf(pm, __shfl_xor(pm, s));
      pmax[r] = pm;
    }
    float dm = fmaxf(fmaxf(kf[0]*(pmax[0]-mrow[0]), kf[1]*(pmax[1]-mrow[1])),
                     fmaxf(kf[2]*(pmax[2]-mrow[2]), kf[3]*(pmax[3]-mrow[3])));
    if (!__all(dm <= 8.f)) {
      #pragma unroll
      for (int r = 0; r < 4; r++) {
        float mn = kf[r] > 0.f ? fmaxf(mrow[r], pmax[r]) : 0.f;
        float sc = kf[r] > 0.f ? __expf(mrow[r] - mn) : 1.f;
        mrow[r] = mn;
        lrow[r] *= sc;
        oacc[0][r] *= sc; oacc[1][r] *= sc; oacc[2][r] *= sc;
      }
    }
    #pragma unroll
    for (int r = 0; r < 4; r++) {
      float p0 = kf[r] > 0.f ? __expf(sf[0][r] - mrow[r]) : 1.f;
      float p1 = kf[r] > 0.f ? __expf(sf[1][r] - mrow[r]) : 1.f;
      float p2 = kf[r] > 0.f ? __expf(sf[2][r] - mrow[r]) : 1.f;
      float p3 = kf[r] > 0.f ? __expf(sf[3][r] - mrow[r]) : 1.f;
      p[0][r]=p0; p[1][r]=p1; p[2][r]=p2; p[3][r]=p3;
      float ps = p0+p1+p2+p3;
      #pragma unroll
      for (int s = 1; s < 16; s <<= 1) ps += __shfl_xor(ps, s);
      lrow[r] += ps;
    }
    #pragma unroll
    for (int f = 0; f < 4; f++)
      #pragma unroll
      for (int r = 0; r < 4; r++)
        Ps[w][(g*4 + r)*72 + f*16 + l15] = f2bf(p[f][r]);
    bf16x8 pa0 = *(const bf16x8*)&Ps[w][l15*72 + g*8];
    bf16x8 pa1 = *(const bf16x8*)&Ps[w][l15*72 + 32 + g*8];
    #pragma unroll
    for (int df = 0; df < 3; df++) {
      bf16x8 vb0 = *(const bf16x8*)&Vt[(df*16 + l15)*72 + g*8];
      bf16x8 vb1 = *(const bf16x8*)&Vt[(df*16 + l15)*72 + 32 + g*8];
      oacc[df] = __builtin_amdgcn_mfma_f32_16x16x32_bf16(pa0, vb0, oacc[df], 0, 0, 0);
      oacc[df] = __builtin_amdgcn_mfma_f32_16x16x32_bf16(pa1, vb1, oacc[df], 0, 0, 0);
    }
  };

  uint4 ka0, ka1, kb0_, kb1_;
  uint2 va[4], vb_[4];
  loadKV(0, ka0, ka1, va);
  __syncthreads();

  qf0 = *(const bf16x8*)&Qs[(wq + l15)*72 + g*8];
  qf1 = *(const bf16x8*)&Qs[(wq + l15)*72 + 32 + g*8];

  for (int kt = 0; kt < 16; kt += 2) {
    writeKV(ka0, ka1, va);
    asm volatile("s_waitcnt lgkmcnt(0)" ::: "memory");
    __builtin_amdgcn_sched_barrier(0);
    __builtin_amdgcn_s_barrier();
    __builtin_amdgcn_sched_barrier(0);
    loadKV(kt + 1, kb0_, kb1_, vb_);
    compute();
    __builtin_amdgcn_sched_barrier(0);
    __builtin_amdgcn_s_barrier();
    writeKV(kb0_, kb1_, vb_);
    asm volatile("s_waitcnt lgkmcnt(0)" ::: "memory");
    __builtin_amdgcn_sched_barrier(0);
    __builtin_amdgcn_s_barrier();
    __builtin_amdgcn_sched_barrier(0);
    if (kt + 2 < 16) loadKV(kt + 2, ka0, ka1, va);
    compute();
    if (kt + 2 < 16) {
      __builtin_amdgcn_sched_barrier(0);
      __builtin_amdgcn_s_barrier();
    }
  }

  #pragma unroll
  for (int r = 0; r < 4; r++) {
    float inv = 1.f / lrow[r];
    size_t qrow = (size_t)(b*NQn + wq + g*4 + r);
    #pragma unroll
    for (int df = 0; df < 3; df++)
      ob[qrow*Cd + h*DHn + df*16 + l15] = f2bf(oacc[df][r] * inv);
  }
}

// --------------------------------------------------------------------------
extern "C" void kernel_launch(void* const* d_in, const int* in_sizes, int n_in,
                              void* d_out, int out_size, void* d_ws, size_t ws_size,
                              hipStream_t stream) {
  (void)in_sizes; (void)n_in; (void)out_size; (void)ws_size;
  const float* x   = (const float*)d_in[0];
  const float* ctx = (const float*)d_in[1];
  const u8*    msk = (const u8*)   d_in[2];
  const float* Wq  = (const float*)d_in[3];
  const float* bq  = (const float*)d_in[4];
  const float* Wkv = (const float*)d_in[5];
  const float* bkv = (const float*)d_in[6];
  const float* Wo  = (const float*)d_in[7];
  const float* bo  = (const float*)d_in[8];
  const float* gc  = (const float*)d_in[9];
  const float* bc  = (const float*)d_in[10];
  const float* W1  = (const float*)d_in[11];
  const float* b1  = (const float*)d_in[12];
  const float* W2  = (const float*)d_in[13];
  const float* b2  = (const float*)d_in[14];
  float* out = (float*)d_out;

  char* ws = (char*)d_ws;
  size_t off = 0;
  auto bump = [&](size_t bytes) -> size_t {
    size_t o = off; off += (bytes + 255) & ~(size_t)255; return o;
  };
  const size_t act = (size_t)ROWSX * Cd * 2;
  size_t o_keep = bump(ROWSX);
  size_t o_xn   = bump(act);
  size_t o_q    = bump(act);
  size_t o_ob   = bump(act);
  size_t o_x1   = bump(act);
  size_t o_hid  = bump((size_t)ROWSX * HIDn * 2);
  size_t o_wtq  = bump((size_t)Cd*Cd*2);
  size_t o_wtkv = bump((size_t)Cd*2*Cd*2);
  size_t o_wto  = bump((size_t)Cd*Cd*2);
  size_t o_wt1  = bump((size_t)Cd*HIDn*2);
  size_t o_wt2  = bump((size_t)HIDn*Cd*2);
  size_t o_cst  = bump((size_t)ROWSC * 2 * 4);   // ctx stats (mean,rstd)
  size_t o_x1st = bump((size_t)ROWSX * 2 * 4);   // x1 stats
  size_t o_kv   = bump((size_t)CBc * NCn * 2 * Cd * 2);

  u8*    keep = (u8*)(ws + o_keep);
  u16*   xn   = (u16*)(ws + o_xn);
  u16*   qb   = (u16*)(ws + o_q);
  u16*   obuf = (u16*)(ws + o_ob);
  u16*   x1b  = (u16*)(ws + o_x1);
  u16*   hidb = (u16*)(ws + o_hid);
  u16*   wtq  = (u16*)(ws + o_wtq);
  u16*   wtkv = (u16*)(ws + o_wtkv);
  u16*   wto  = (u16*)(ws + o_wto);
  u16*   wt1  = (u16*)(ws + o_wt1);
  u16*   wt2  = (u16*)(ws + o_wt2);
  float* cst  = (float*)(ws + o_cst);
  float* x1st = (float*)(ws + o_x1st);
  u16*   kvb  = (u16*)(ws + o_kv);

  decode_mask_kernel<<<1, 256, 0, stream>>>(msk, keep);

  WPack wp;
  wp.W[0]=Wq;  wp.WT[0]=wtq;  wp.K[0]=Cd;   wp.N[0]=Cd;
  wp.W[1]=Wkv; wp.WT[1]=wtkv; wp.K[1]=Cd;   wp.N[1]=2*Cd;
  wp.W[2]=Wo;  wp.WT[2]=wto;  wp.K[2]=Cd;   wp.N[2]=Cd;
  wp.W[3]=W1;  wp.WT[3]=wt1;  wp.K[3]=Cd;   wp.N[3]=HIDn;
  wp.W[4]=W2;  wp.WT[4]=wt2;  wp.K[4]=HIDn; wp.N[4]=Cd;
  wp.off[0]=0; wp.off[1]=36; wp.off[2]=108; wp.off[3]=144; wp.off[4]=288; wp.off[5]=432;
  wconvt_all_kernel<<<432, 256, 0, stream>>>(wp);

  // ctx row stats (replaces materialized LN(ctx))
  row_stats_kernel<1><<<ROWSC/4, 256, 0, stream>>>(ctx, cst, 1e-5f);

  lnorm_kernel<0,1><<<ROWSX/4, 256, 0, stream>>>(x, nullptr, nullptr, xn, 1e-6f);

  // q = (LN(x) @ Wq + bq) * ATT_SCALE
  mgemm_kernel<0,0,0,0,1><<<3*(ROWSX/128), 256, 0, stream>>>(
      xn, wtq, bq, nullptr, qb, ROWSX, Cd, Cd, 3);

  for (int b0 = 0; b0 < BTn; b0 += CBc) {
    // kv = (LN_affine(ctx) @ Wkv + bkv), LN fused into A-staging
    mgemm256ln_kernel<1,1,0><<<3*(CBc*NCn/128), 512, 0, stream>>>(
        ctx + (size_t)b0*NCn*Cd, cst + (size_t)b0*NCn*2, gc, bc,
        wtkv, bkv, kvb, CBc*NCn, 2*Cd, Cd, 3);
    fattn_kernel<<<dim3(Hn, CBc), 256, 0, stream>>>(qb, kvb, keep, obuf, b0);
  }

  // x1 = x + o @ Wo + bo
  mgemm_kernel<0,1,1,0,0><<<3*(ROWSX/128), 256, 0, stream>>>(
      obuf, wto, bo, x, x1b, ROWSX, Cd, Cd, 3);

  // x1 row stats (replaces materialized LN(x1))
  row_stats_kernel<0><<<ROWSX/4, 256, 0, stream>>>(x1b, x1st, 1e-6f);

  // hidden = gelu(LN(x1) @ W1 + b1), LN fused into A-staging (bf16 A)
  mgemm256ln_kernel<0,0,1><<<6*(ROWSX/128), 512, 0, stream>>>(
      x1b, x1st, nullptr, nullptr, wt1, b1, hidb, ROWSX, HIDn, Cd, 6);

  // out = x1 + hidden @ W2 + b2
  mgemm_kernel<0,1,0,1,0><<<3*(ROWSX/128), 256, 0, stream>>>(
      hidb, wt2, b2, x1b, out, ROWSX, Cd, HIDn, 3);
}

// Round 13
// 575.355 us; speedup vs baseline: 1.4231x; 1.4231x over previous
//
#include <hip/hip_runtime.h>
#include <hip/hip_bf16.h>
#include <math.h>

typedef unsigned int  u32;
typedef unsigned short u16;
typedef unsigned char u8;

#define BTn   192
#define NQn   64
#define NCn   1024
#define Cd    384
#define Hn    8
#define DHn   48
#define HIDn  1536
#define ROWSX (BTn*NQn)     /* 12288 */
#define ROWSC (BTn*NCn)     /* 196608 */
#define ATT_SCALE 0.14433756729740643f
#define CBc   64            /* batch chunk: kvb+cnb = 151 MB, L3-resident */

typedef __bf16 bf16x8 __attribute__((ext_vector_type(8)));
typedef float  f32x4  __attribute__((ext_vector_type(4)));

#define GLL16(gp, lp) __builtin_amdgcn_global_load_lds( \
    (const __attribute__((address_space(1))) void*)(gp), \
    (__attribute__((address_space(3))) void*)(lp), 16, 0, 0)

__device__ __forceinline__ float bf2f(u32 u) {
  union { u32 i; float f; } v; v.i = u << 16; return v.f;
}
__device__ __forceinline__ u16 f2bf(float f) {
  union { float f; u32 i; } v; v.f = f;
  u32 x = v.i;
  x += 0x7fffu + ((x >> 16) & 1u);
  return (u16)(x >> 16);
}
__device__ __forceinline__ void decode8(uint4 r, float* v) {
  v[0]=bf2f(r.x & 0xffffu); v[1]=bf2f(r.x >> 16);
  v[2]=bf2f(r.y & 0xffffu); v[3]=bf2f(r.y >> 16);
  v[4]=bf2f(r.z & 0xffffu); v[5]=bf2f(r.z >> 16);
  v[6]=bf2f(r.w & 0xffffu); v[7]=bf2f(r.w >> 16);
}
__device__ __forceinline__ float gelu_f(float x) {
  float x3 = x*x*x;
  float z = 0.7978845608028654f*x + 0.035677408136300125f*x3;
  float e = __expf(2.f*z);
  float th = 1.f - 2.f/(e+1.f);
  return 0.5f*x*(1.f+th);
}

// ---------------- mask decode (robust to u8 / i32 / bf16 / f32 storage) ---
__global__ void decode_mask_kernel(const u8* __restrict__ m, u8* __restrict__ keep) {
  __shared__ int flags[3];
  int t = threadIdx.x;
  if (t < 3) flags[t] = 0;
  __syncthreads();
  int nonbin = 0, oddset = 0, low01 = 0;
  for (int i = t; i < ROWSX; i += 256) {
    u32 b = m[i];
    if (b > 1u) nonbin = 1;
    if ((i & 3) && b) oddset = 1;
    if (((i & 3) < 2) && b) low01 = 1;
  }
  if (nonbin) flags[0] = 1;
  if (oddset) flags[1] = 1;
  if (low01)  flags[2] = 1;
  __syncthreads();
  int mode = flags[0] ? (flags[2] ? 2 : 3) : (flags[1] ? 1 : 0);
  for (int i = t; i < ROWSX; i += 256) {
    u8 k;
    if (mode == 2)      k = (m[2*i] | m[2*i+1]) ? 1 : 0;
    else if (mode == 3) k = (((const float*)m)[i] != 0.f) ? 1 : 0;
    else if (mode == 1) k = m[i] ? 1 : 0;
    else                k = (((const int*)m)[i] != 0) ? 1 : 0;
    keep[i] = k;
  }
}

// ---------------- fused LayerNorm -> bf16 (wave per row) ------------------
template<int AFF, int SRCF32>
__global__ __launch_bounds__(256) void lnorm_kernel(
    const void* __restrict__ srcv, const float* __restrict__ gw,
    const float* __restrict__ bw, u16* __restrict__ dst, float eps)
{
  const int row  = blockIdx.x * 4 + (threadIdx.x >> 6);
  const int lane = threadIdx.x & 63;
  float v[6];
  if (SRCF32) {
    const float2* p = (const float2*)((const float*)srcv + (size_t)row*Cd);
    #pragma unroll
    for (int i = 0; i < 3; i++) { float2 u = p[lane + 64*i]; v[2*i]=u.x; v[2*i+1]=u.y; }
  } else {
    const u32* p = (const u32*)((const u16*)srcv + (size_t)row*Cd);
    #pragma unroll
    for (int i = 0; i < 3; i++) { u32 u = p[lane + 64*i]; v[2*i]=bf2f(u&0xffffu); v[2*i+1]=bf2f(u>>16); }
  }
  float s  = v[0]+v[1]+v[2]+v[3]+v[4]+v[5];
  float s2 = v[0]*v[0]+v[1]*v[1]+v[2]*v[2]+v[3]*v[3]+v[4]*v[4]+v[5]*v[5];
  #pragma unroll
  for (int o = 32; o >= 1; o >>= 1) { s += __shfl_xor(s, o); s2 += __shfl_xor(s2, o); }
  float mean = s * (1.0f/Cd);
  float var  = s2 * (1.0f/Cd) - mean*mean;
  var = var > 0.f ? var : 0.f;
  float rstd = rsqrtf(var + eps);
  u32* d32 = (u32*)(dst + (size_t)row*Cd);
  #pragma unroll
  for (int i = 0; i < 3; i++) {
    float y0 = (v[2*i]   - mean) * rstd;
    float y1 = (v[2*i+1] - mean) * rstd;
    if (AFF) {
      float2 gg = *(const float2*)(gw + 2*(lane + 64*i));
      float2 bb = *(const float2*)(bw + 2*(lane + 64*i));
      y0 = y0*gg.x + bb.x;
      y1 = y1*gg.y + bb.y;
    }
    d32[lane + 64*i] = (u32)f2bf(y0) | ((u32)f2bf(y1) << 16);
  }
}

// ------- batched weight transpose+convert: W[K][N] f32 -> WT[N][K] bf16 ---
struct WPack {
  const float* W[5];
  u16* WT[5];
  int K[5];
  int N[5];
  int off[6];
};
__global__ __launch_bounds__(256) void wconvt_all_kernel(WPack p) {
  __shared__ u16 tile[64][66];
  const int bid = blockIdx.x;
  int s = 0;
  #pragma unroll
  for (int i = 1; i < 5; i++) if (bid >= p.off[i]) s = i;
  const float* W = p.W[s];
  u16* WT = p.WT[s];
  const int K = p.K[s], N = p.N[s];
  const int lb = bid - p.off[s];
  const int t  = threadIdx.x;
  const int nt = N >> 6;
  const int bk = lb / nt, bn = lb % nt;
  const int q  = t >> 6;
  const int nl = t & 63;
  #pragma unroll
  for (int r = 0; r < 16; r++) {
    int k = q*16 + r;
    tile[nl][k] = f2bf(W[(size_t)(bk*64 + k)*N + bn*64 + nl]);
  }
  __syncthreads();
  #pragma unroll
  for (int r = 0; r < 16; r++) {
    int n = q*16 + r;
    WT[(size_t)(bn*64 + n)*K + bk*64 + nl] = tile[n][nl];
  }
}

// ---------------- MFMA GEMM 128x128 (4 waves): 3-buffer depth-2 -----------
template<int GEL, int RES, int RF32, int OF32, int SCL>
__global__ __launch_bounds__(256) void mgemm_kernel(
    const u16* __restrict__ A, const u16* __restrict__ WT,
    const float* __restrict__ bias, const void* __restrict__ resv,
    void* __restrict__ Coutv, int M, int N, int K, int nx)
{
  __shared__ u16 As[3][4096];
  __shared__ u16 Bs[3][4096];
  const int t = threadIdx.x;
  const int w = t >> 6, l = t & 63, l15 = l & 15, g = l >> 4;

  const int nwg = gridDim.x;
  const int bid = blockIdx.x;
  const int wg  = (bid & 7) * (nwg >> 3) + (bid >> 3);
  const int n0 = (wg % nx) * 128, m0 = (wg / nx) * 128;
  const int wm = (w & 1) * 64, wn = (w >> 1) * 64;

  const int arow = t >> 2;
  const int swk  = (t >> 3) & 3;
  const int acol = ((t & 3) ^ swk) * 8;
  const u16* Ag = A  + (size_t)(m0 + arow) * K + acol;
  const u16* Wg = WT + (size_t)(n0 + arow) * K + acol;
  const size_t rowskip = (size_t)64 * K;

  const int xk   = (l15 >> 1) & 3;
  const int goff = ((g ^ xk) << 3);

  f32x4 acc[4][4];
  #pragma unroll
  for (int i = 0; i < 4; i++)
    #pragma unroll
    for (int j = 0; j < 4; j++) acc[i][j] = (f32x4){0.f, 0.f, 0.f, 0.f};

  const int nIter = K >> 5;

#define STAGE(nb, kk) do { \
    GLL16(Ag + (kk),           &As[nb][t*8]); \
    GLL16(Ag + (kk) + rowskip, &As[nb][2048 + t*8]); \
    GLL16(Wg + (kk),           &Bs[nb][t*8]); \
    GLL16(Wg + (kk) + rowskip, &Bs[nb][2048 + t*8]); \
  } while (0)

#define BODY(BUF, IT) do { \
    const int it_ = (IT); \
    if (it_ + 2 < nIter) { \
      STAGE((BUF + 2) % 3, (it_ + 2) << 5); \
      asm volatile("s_waitcnt vmcnt(8)" ::: "memory"); \
    } else if (it_ + 1 < nIter) { \
      asm volatile("s_waitcnt vmcnt(4)" ::: "memory"); \
    } else { \
      asm volatile("s_waitcnt vmcnt(0)" ::: "memory"); \
    } \
    __builtin_amdgcn_s_barrier(); \
    __builtin_amdgcn_sched_barrier(0); \
    { \
      bf16x8 af[4], bfv[4]; \
      _Pragma("unroll") \
      for (int i = 0; i < 4; i++) \
        af[i] = *(const bf16x8*)&As[BUF][(wm + i*16 + l15)*32 + goff]; \
      _Pragma("unroll") \
      for (int j = 0; j < 4; j++) \
        bfv[j] = *(const bf16x8*)&Bs[BUF][(wn + j*16 + l15)*32 + goff]; \
      _Pragma("unroll") \
      for (int i = 0; i < 4; i++) \
        _Pragma("unroll") \
        for (int j = 0; j < 4; j++) \
          acc[i][j] = __builtin_amdgcn_mfma_f32_16x16x32_bf16(bfv[j], af[i], acc[i][j], 0, 0, 0); \
    } \
    __builtin_amdgcn_sched_barrier(0); \
    __builtin_amdgcn_s_barrier(); \
  } while (0)

  STAGE(0, 0);
  STAGE(1, 32);
  for (int it0 = 0; it0 < nIter; it0 += 3) {
    BODY(0, it0);
    BODY(1, it0 + 1);
    BODY(2, it0 + 2);
  }
#undef BODY
#undef STAGE

  const float* resf = (const float*)resv;
  const u16*   resb = (const u16*)resv;
  float* Cf = (float*)Coutv;
  u16*   Cb = (u16*)Coutv;
  #pragma unroll
  for (int j = 0; j < 4; j++) {
    const int nb = n0 + wn + j*16 + g*4;
    const float4 bv = *(const float4*)&bias[nb];
    #pragma unroll
    for (int i = 0; i < 4; i++) {
      const int m = m0 + wm + i*16 + l15;
      float c0 = acc[i][j][0] + bv.x;
      float c1 = acc[i][j][1] + bv.y;
      float c2 = acc[i][j][2] + bv.z;
      float c3 = acc[i][j][3] + bv.w;
      if (SCL) { c0 *= ATT_SCALE; c1 *= ATT_SCALE; c2 *= ATT_SCALE; c3 *= ATT_SCALE; }
      if (GEL) { c0 = gelu_f(c0); c1 = gelu_f(c1); c2 = gelu_f(c2); c3 = gelu_f(c3); }
      if (RES) {
        if (RF32) {
          float4 r = *(const float4*)&resf[(size_t)m*N + nb];
          c0 += r.x; c1 += r.y; c2 += r.z; c3 += r.w;
        } else {
          uint2 r = *(const uint2*)&resb[(size_t)m*N + nb];
          c0 += bf2f(r.x & 0xffffu); c1 += bf2f(r.x >> 16);
          c2 += bf2f(r.y & 0xffffu); c3 += bf2f(r.y >> 16);
        }
      }
      if (OF32) {
        *(float4*)&Cf[(size_t)m*N + nb] = make_float4(c0, c1, c2, c3);
      } else {
        uint2 pk = make_uint2((u32)f2bf(c0) | ((u32)f2bf(c1) << 16),
                              (u32)f2bf(c2) | ((u32)f2bf(c3) << 16));
        *(uint2*)&Cb[(size_t)m*N + nb] = pk;
      }
    }
  }
}

// ---------------- MFMA GEMM 128x256 (8 waves): 3-buffer depth-2 -----------
template<int GEL, int RES, int RF32, int OF32>
__global__ __launch_bounds__(512, 4) void mgemm256_kernel(
    const u16* __restrict__ A, const u16* __restrict__ WT,
    const float* __restrict__ bias, const void* __restrict__ resv,
    void* __restrict__ Coutv, int M, int N, int K, int nx)
{
  __shared__ u16 As[3][4096];   // 128 x 32
  __shared__ u16 Bs[3][8192];   // 256 x 32
  const int t = threadIdx.x;                 // 0..511
  const int w = t >> 6, l = t & 63, l15 = l & 15, g = l >> 4;

  const int nwg = gridDim.x;
  const int bid = blockIdx.x;
  const int wg  = (bid & 7) * (nwg >> 3) + (bid >> 3);
  const int n0 = (wg % nx) * 256, m0 = (wg / nx) * 128;
  const int wm = (w & 1) * 64, wn = (w >> 1) * 64;   // wn 0..192

  const int arow = t >> 2;                   // 0..127
  const int swk  = (t >> 3) & 3;
  const int acol = ((t & 3) ^ swk) * 8;
  const u16* Ag = A  + (size_t)(m0 + arow) * K + acol;
  const u16* Wg = WT + (size_t)(n0 + arow) * K + acol;
  const size_t rowskipB = (size_t)128 * K;

  const int xk   = (l15 >> 1) & 3;
  const int goff = ((g ^ xk) << 3);

  f32x4 acc[4][4];
  #pragma unroll
  for (int i = 0; i < 4; i++)
    #pragma unroll
    for (int j = 0; j < 4; j++) acc[i][j] = (f32x4){0.f, 0.f, 0.f, 0.f};

  const int nIter = K >> 5;

#define STAGE(nb, kk) do { \
    GLL16(Ag + (kk),            &As[nb][t*8]); \
    GLL16(Wg + (kk),            &Bs[nb][t*8]); \
    GLL16(Wg + (kk) + rowskipB, &Bs[nb][4096 + t*8]); \
  } while (0)

#define BODY(BUF, IT) do { \
    const int it_ = (IT); \
    if (it_ + 2 < nIter) { \
      STAGE((BUF + 2) % 3, (it_ + 2) << 5); \
      asm volatile("s_waitcnt vmcnt(6)" ::: "memory"); \
    } else if (it_ + 1 < nIter) { \
      asm volatile("s_waitcnt vmcnt(3)" ::: "memory"); \
    } else { \
      asm volatile("s_waitcnt vmcnt(0)" ::: "memory"); \
    } \
    __builtin_amdgcn_s_barrier(); \
    __builtin_amdgcn_sched_barrier(0); \
    { \
      bf16x8 af[4], bfv[4]; \
      _Pragma("unroll") \
      for (int i = 0; i < 4; i++) \
        af[i] = *(const bf16x8*)&As[BUF][(wm + i*16 + l15)*32 + goff]; \
      _Pragma("unroll") \
      for (int j = 0; j < 4; j++) \
        bfv[j] = *(const bf16x8*)&Bs[BUF][(wn + j*16 + l15)*32 + goff]; \
      _Pragma("unroll") \
      for (int i = 0; i < 4; i++) \
        _Pragma("unroll") \
        for (int j = 0; j < 4; j++) \
          acc[i][j] = __builtin_amdgcn_mfma_f32_16x16x32_bf16(bfv[j], af[i], acc[i][j], 0, 0, 0); \
    } \
    __builtin_amdgcn_sched_barrier(0); \
    __builtin_amdgcn_s_barrier(); \
  } while (0)

  STAGE(0, 0);
  STAGE(1, 32);
  for (int it0 = 0; it0 < nIter; it0 += 3) {
    BODY(0, it0);
    BODY(1, it0 + 1);
    BODY(2, it0 + 2);
  }
#undef BODY
#undef STAGE

  const float* resf = (const float*)resv;
  const u16*   resb = (const u16*)resv;
  float* Cf = (float*)Coutv;
  u16*   Cb = (u16*)Coutv;
  #pragma unroll
  for (int j = 0; j < 4; j++) {
    const int nb = n0 + wn + j*16 + g*4;
    const float4 bv = *(const float4*)&bias[nb];
    #pragma unroll
    for (int i = 0; i < 4; i++) {
      const int m = m0 + wm + i*16 + l15;
      float c0 = acc[i][j][0] + bv.x;
      float c1 = acc[i][j][1] + bv.y;
      float c2 = acc[i][j][2] + bv.z;
      float c3 = acc[i][j][3] + bv.w;
      if (GEL) { c0 = gelu_f(c0); c1 = gelu_f(c1); c2 = gelu_f(c2); c3 = gelu_f(c3); }
      if (RES) {
        if (RF32) {
          float4 r = *(const float4*)&resf[(size_t)m*N + nb];
          c0 += r.x; c1 += r.y; c2 += r.z; c3 += r.w;
        } else {
          uint2 r = *(const uint2*)&resb[(size_t)m*N + nb];
          c0 += bf2f(r.x & 0xffffu); c1 += bf2f(r.x >> 16);
          c2 += bf2f(r.y & 0xffffu); c3 += bf2f(r.y >> 16);
        }
      }
      if (OF32) {
        *(float4*)&Cf[(size_t)m*N + nb] = make_float4(c0, c1, c2, c3);
      } else {
        uint2 pk = make_uint2((u32)f2bf(c0) | ((u32)f2bf(c1) << 16),
                              (u32)f2bf(c2) | ((u32)f2bf(c3) << 16));
        *(uint2*)&Cb[(size_t)m*N + nb] = pk;
      }
    }
  }
}

// ---------------- flash attention, MFMA, one block per (b,h) --------------
// Q pre-scaled in Q-proj; T13 defer-max (THR=8); chunked over batches.
__global__ __launch_bounds__(256) void fattn_kernel(
    const u16* __restrict__ qb, const u16* __restrict__ kvb,
    const u8* __restrict__ keep, u16* __restrict__ ob, int b0)
{
  __shared__ u16 Qs[64*72];
  __shared__ u16 Ks[64*72];
  __shared__ u16 Vt[48*72];
  __shared__ u16 Ps[4][16*72];

  const int t = threadIdx.x;
  const int w = t >> 6, l = t & 63, l15 = l & 15, g = l >> 4;
  const int h = blockIdx.x, bz = blockIdx.y;
  const int b = b0 + bz;
  const int wq = w * 16;
  const int krow0 = t / 6, kp0 = t % 6;
  const int krow1 = (256 + t) / 6, kp1 = (256 + t) % 6;   // t<128
  const int vdq = (t >> 4) * 4, vkq = (t & 15) * 4;       // t<192

  for (int i = t; i < 2304; i += 256) { ((u32*)Qs)[i] = 0; ((u32*)Ks)[i] = 0; }
  __syncthreads();

  // stage Q (already scaled by ATT_SCALE in Q-proj epilogue)
  for (int i = t; i < 384; i += 256) {
    int row = i / 6, p = i % 6;
    *(uint4*)&Qs[row*72 + p*8] =
        *(const uint4*)(qb + (size_t)(b*NQn + row)*Cd + h*DHn + p*8);
  }

  u32 kw = *(const u32*)&keep[b*NQn + wq + g*4];
  float kf[4];
  #pragma unroll
  for (int r = 0; r < 4; r++) kf[r] = ((kw >> (8*r)) & 0xffu) ? 1.f : 0.f;

  float mrow[4], lrow[4];
  f32x4 oacc[3];
  #pragma unroll
  for (int r = 0; r < 4; r++) { mrow[r] = kf[r] > 0.f ? -3.0e38f : 0.f; lrow[r] = 0.f; }
  #pragma unroll
  for (int d = 0; d < 3; d++) oacc[d] = (f32x4){0.f, 0.f, 0.f, 0.f};

  auto loadKV = [&](int kt, uint4& KR0, uint4& KR1, uint2* V) {
    const u16* base = kvb + ((size_t)bz*NCn + (size_t)kt*64) * (2*(size_t)Cd);
    KR0 = *(const uint4*)(base + (size_t)krow0*(2*Cd) + h*DHn + kp0*8);
    if (t < 128)
      KR1 = *(const uint4*)(base + (size_t)krow1*(2*Cd) + h*DHn + kp1*8);
    if (t < 192) {
      const u16* vs = base + (size_t)vkq*(2*Cd) + Cd + h*DHn + vdq;
      V[0] = *(const uint2*)(vs);
      V[1] = *(const uint2*)(vs + 2*Cd);
      V[2] = *(const uint2*)(vs + 4*Cd);
      V[3] = *(const uint2*)(vs + 6*Cd);
    }
  };
  auto writeKV = [&](const uint4& KR0, const uint4& KR1, const uint2* V) {
    *(uint4*)&Ks[krow0*72 + kp0*8] = KR0;
    if (t < 128) *(uint4*)&Ks[krow1*72 + kp1*8] = KR1;
    if (t < 192) {
      #pragma unroll
      for (int jj = 0; jj < 4; jj++) {
        u16 o4[4] = {((const u16*)&V[0])[jj], ((const u16*)&V[1])[jj],
                     ((const u16*)&V[2])[jj], ((const u16*)&V[3])[jj]};
        *(uint2*)&Vt[(vdq+jj)*72 + vkq] = *(uint2*)o4;
      }
    }
  };

  bf16x8 qf0, qf1;
  auto compute = [&]() {
    f32x4 sf[4];
    #pragma unroll
    for (int f = 0; f < 4; f++) {
      bf16x8 ka = *(const bf16x8*)&Ks[(f*16 + l15)*72 + g*8];
      bf16x8 kb = *(const bf16x8*)&Ks[(f*16 + l15)*72 + 32 + g*8];
      f32x4 z = (f32x4){0.f, 0.f, 0.f, 0.f};
      z = __builtin_amdgcn_mfma_f32_16x16x32_bf16(qf0, ka, z, 0, 0, 0);
      sf[f] = __builtin_amdgcn_mfma_f32_16x16x32_bf16(qf1, kb, z, 0, 0, 0);
    }
    float p[4][4], pmax[4];
    #pragma unroll
    for (int r = 0; r < 4; r++) {
      float pm = fmaxf(fmaxf(sf[0][r], sf[1][r]), fmaxf(sf[2][r], sf[3][r]));
      #pragma unroll
      for (int s = 1; s < 16; s <<= 1) pm = fmaxf(pm, __shfl_xor(pm, s));
      pmax[r] = pm;
    }
    // T13 defer-max: skip rescale when wave-wide max growth <= 8
    float dm = fmaxf(fmaxf(kf[0]*(pmax[0]-mrow[0]), kf[1]*(pmax[1]-mrow[1])),
                     fmaxf(kf[2]*(pmax[2]-mrow[2]), kf[3]*(pmax[3]-mrow[3])));
    if (!__all(dm <= 8.f)) {
      #pragma unroll
      for (int r = 0; r < 4; r++) {
        float mn = kf[r] > 0.f ? fmaxf(mrow[r], pmax[r]) : 0.f;
        float sc = kf[r] > 0.f ? __expf(mrow[r] - mn) : 1.f;
        mrow[r] = mn;
        lrow[r] *= sc;
        oacc[0][r] *= sc; oacc[1][r] *= sc; oacc[2][r] *= sc;
      }
    }
    #pragma unroll
    for (int r = 0; r < 4; r++) {
      float p0 = kf[r] > 0.f ? __expf(sf[0][r] - mrow[r]) : 1.f;
      float p1 = kf[r] > 0.f ? __expf(sf[1][r] - mrow[r]) : 1.f;
      float p2 = kf[r] > 0.f ? __expf(sf[2][r] - mrow[r]) : 1.f;
      float p3 = kf[r] > 0.f ? __expf(sf[3][r] - mrow[r]) : 1.f;
      p[0][r]=p0; p[1][r]=p1; p[2][r]=p2; p[3][r]=p3;
      float ps = p0+p1+p2+p3;
      #pragma unroll
      for (int s = 1; s < 16; s <<= 1) ps += __shfl_xor(ps, s);
      lrow[r] += ps;
    }
    #pragma unroll
    for (int f = 0; f < 4; f++)
      #pragma unroll
      for (int r = 0; r < 4; r++)
        Ps[w][(g*4 + r)*72 + f*16 + l15] = f2bf(p[f][r]);
    bf16x8 pa0 = *(const bf16x8*)&Ps[w][l15*72 + g*8];
    bf16x8 pa1 = *(const bf16x8*)&Ps[w][l15*72 + 32 + g*8];
    #pragma unroll
    for (int df = 0; df < 3; df++) {
      bf16x8 vb0 = *(const bf16x8*)&Vt[(df*16 + l15)*72 + g*8];
      bf16x8 vb1 = *(const bf16x8*)&Vt[(df*16 + l15)*72 + 32 + g*8];
      oacc[df] = __builtin_amdgcn_mfma_f32_16x16x32_bf16(pa0, vb0, oacc[df], 0, 0, 0);
      oacc[df] = __builtin_amdgcn_mfma_f32_16x16x32_bf16(pa1, vb1, oacc[df], 0, 0, 0);
    }
  };

  uint4 ka0, ka1, kb0_, kb1_;
  uint2 va[4], vb_[4];
  loadKV(0, ka0, ka1, va);
  __syncthreads();

  qf0 = *(const bf16x8*)&Qs[(wq + l15)*72 + g*8];
  qf1 = *(const bf16x8*)&Qs[(wq + l15)*72 + 32 + g*8];

  for (int kt = 0; kt < 16; kt += 2) {
    writeKV(ka0, ka1, va);
    asm volatile("s_waitcnt lgkmcnt(0)" ::: "memory");
    __builtin_amdgcn_sched_barrier(0);
    __builtin_amdgcn_s_barrier();
    __builtin_amdgcn_sched_barrier(0);
    loadKV(kt + 1, kb0_, kb1_, vb_);
    compute();
    __builtin_amdgcn_sched_barrier(0);
    __builtin_amdgcn_s_barrier();
    writeKV(kb0_, kb1_, vb_);
    asm volatile("s_waitcnt lgkmcnt(0)" ::: "memory");
    __builtin_amdgcn_sched_barrier(0);
    __builtin_amdgcn_s_barrier();
    __builtin_amdgcn_sched_barrier(0);
    if (kt + 2 < 16) loadKV(kt + 2, ka0, ka1, va);
    compute();
    if (kt + 2 < 16) {
      __builtin_amdgcn_sched_barrier(0);
      __builtin_amdgcn_s_barrier();
    }
  }

  #pragma unroll
  for (int r = 0; r < 4; r++) {
    float inv = 1.f / lrow[r];
    size_t qrow = (size_t)(b*NQn + wq + g*4 + r);
    #pragma unroll
    for (int df = 0; df < 3; df++)
      ob[qrow*Cd + h*DHn + df*16 + l15] = f2bf(oacc[df][r] * inv);
  }
}

// --------------------------------------------------------------------------
extern "C" void kernel_launch(void* const* d_in, const int* in_sizes, int n_in,
                              void* d_out, int out_size, void* d_ws, size_t ws_size,
                              hipStream_t stream) {
  (void)in_sizes; (void)n_in; (void)out_size; (void)ws_size;
  const float* x   = (const float*)d_in[0];
  const float* ctx = (const float*)d_in[1];
  const u8*    msk = (const u8*)   d_in[2];
  const float* Wq  = (const float*)d_in[3];
  const float* bq  = (const float*)d_in[4];
  const float* Wkv = (const float*)d_in[5];
  const float* bkv = (const float*)d_in[6];
  const float* Wo  = (const float*)d_in[7];
  const float* bo  = (const float*)d_in[8];
  const float* gc  = (const float*)d_in[9];
  const float* bc  = (const float*)d_in[10];
  const float* W1  = (const float*)d_in[11];
  const float* b1  = (const float*)d_in[12];
  const float* W2  = (const float*)d_in[13];
  const float* b2  = (const float*)d_in[14];
  float* out = (float*)d_out;

  char* ws = (char*)d_ws;
  size_t off = 0;
  auto bump = [&](size_t bytes) -> size_t {
    size_t o = off; off += (bytes + 255) & ~(size_t)255; return o;
  };
  const size_t act = (size_t)ROWSX * Cd * 2;
  size_t o_keep = bump(ROWSX);
  size_t o_xn   = bump(act);
  size_t o_q    = bump(act);
  size_t o_ob   = bump(act);
  size_t o_x1   = bump(act);
  size_t o_x1n  = bump(act);
  size_t o_hid  = bump((size_t)ROWSX * HIDn * 2);
  size_t o_wtq  = bump((size_t)Cd*Cd*2);
  size_t o_wtkv = bump((size_t)Cd*2*Cd*2);
  size_t o_wto  = bump((size_t)Cd*Cd*2);
  size_t o_wt1  = bump((size_t)Cd*HIDn*2);
  size_t o_wt2  = bump((size_t)HIDn*Cd*2);
  size_t o_cn   = bump((size_t)CBc * NCn * Cd * 2);
  size_t o_kv   = bump((size_t)CBc * NCn * 2 * Cd * 2);

  u8*  keep = (u8*)(ws + o_keep);
  u16* xn   = (u16*)(ws + o_xn);
  u16* qb   = (u16*)(ws + o_q);
  u16* obuf = (u16*)(ws + o_ob);
  u16* x1b  = (u16*)(ws + o_x1);
  u16* x1n  = (u16*)(ws + o_x1n);
  u16* hidb = (u16*)(ws + o_hid);
  u16* wtq  = (u16*)(ws + o_wtq);
  u16* wtkv = (u16*)(ws + o_wtkv);
  u16* wto  = (u16*)(ws + o_wto);
  u16* wt1  = (u16*)(ws + o_wt1);
  u16* wt2  = (u16*)(ws + o_wt2);
  u16* cnb  = (u16*)(ws + o_cn);
  u16* kvb  = (u16*)(ws + o_kv);

  decode_mask_kernel<<<1, 256, 0, stream>>>(msk, keep);

  WPack wp;
  wp.W[0]=Wq;  wp.WT[0]=wtq;  wp.K[0]=Cd;   wp.N[0]=Cd;
  wp.W[1]=Wkv; wp.WT[1]=wtkv; wp.K[1]=Cd;   wp.N[1]=2*Cd;
  wp.W[2]=Wo;  wp.WT[2]=wto;  wp.K[2]=Cd;   wp.N[2]=Cd;
  wp.W[3]=W1;  wp.WT[3]=wt1;  wp.K[3]=Cd;   wp.N[3]=HIDn;
  wp.W[4]=W2;  wp.WT[4]=wt2;  wp.K[4]=HIDn; wp.N[4]=Cd;
  wp.off[0]=0; wp.off[1]=36; wp.off[2]=108; wp.off[3]=144; wp.off[4]=288; wp.off[5]=432;
  wconvt_all_kernel<<<432, 256, 0, stream>>>(wp);

  lnorm_kernel<0,1><<<ROWSX/4, 256, 0, stream>>>(x, nullptr, nullptr, xn, 1e-6f);

  // q = (LN(x) @ Wq + bq) * ATT_SCALE
  mgemm_kernel<0,0,0,0,1><<<3*(ROWSX/128), 256, 0, stream>>>(
      xn, wtq, bq, nullptr, qb, ROWSX, Cd, Cd, 3);

  for (int b0 = 0; b0 < BTn; b0 += CBc) {
    lnorm_kernel<1,1><<<CBc*NCn/4, 256, 0, stream>>>(
        ctx + (size_t)b0*NCn*Cd, gc, bc, cnb, 1e-5f);
    mgemm256_kernel<0,0,0,0><<<3*(CBc*NCn/128), 512, 0, stream>>>(
        cnb, wtkv, bkv, nullptr, kvb, CBc*NCn, 2*Cd, Cd, 3);
    fattn_kernel<<<dim3(Hn, CBc), 256, 0, stream>>>(qb, kvb, keep, obuf, b0);
  }

  // x1 = x + o @ Wo + bo
  mgemm_kernel<0,1,1,0,0><<<3*(ROWSX/128), 256, 0, stream>>>(
      obuf, wto, bo, x, x1b, ROWSX, Cd, Cd, 3);

  lnorm_kernel<0,0><<<ROWSX/4, 256, 0, stream>>>(x1b, nullptr, nullptr, x1n, 1e-6f);

  // hidden = gelu(LN(x1) @ W1 + b1)
  mgemm256_kernel<1,0,0,0><<<6*(ROWSX/128), 512, 0, stream>>>(
      x1n, wt1, b1, nullptr, hidb, ROWSX, HIDn, Cd, 6);

  // out = x1 + hidden @ W2 + b2
  mgemm_kernel<0,1,0,1,0><<<3*(ROWSX/128), 256, 0, stream>>>(
      hidb, wt2, b2, x1b, out, ROWSX, Cd, HIDn, 3);
}